// Round 3
// baseline (7716.756 us; speedup 1.0000x reference)
//
#include <hip/hip_runtime.h>
#include <hip/hip_bf16.h>
#include <hip/hip_cooperative_groups.h>
#include <math.h>

namespace cg = cooperative_groups;

// Problem dims
#define BB 32
#define TE 80
#define FEAT 4096
#define HH 256
#define W2V 256
#define TD 30
#define VV 32000
#define G4 1024   // 4*H

typedef unsigned short u16;
typedef unsigned int u32;
using f32x4 = __attribute__((ext_vector_type(4))) float;
using bf16x8 = __attribute__((ext_vector_type(8))) short;

__device__ __forceinline__ float sigm(float x) { return 1.0f / (1.0f + expf(-x)); }
__device__ __forceinline__ u16 f2bf(float f) {
  u32 u = __float_as_uint(f);
  u32 r = (u + 0x7FFFu + ((u >> 16) & 1u)) >> 16;
  return (u16)r;
}
__device__ __forceinline__ float bflo(u32 p) { return __uint_as_float(p << 16); }
__device__ __forceinline__ float bfhi(u32 p) { return __uint_as_float(p & 0xFFFF0000u); }

// ---------------------------------------------------------------------------
// init: zero states (h1b0,h1b1,h2b0,h2b1,c1,c2 = 6*8192); bias sums
__global__ __launch_bounds__(256) void init_kernel(
    const float* __restrict__ b_ih1, const float* __restrict__ b_hh1,
    const float* __restrict__ b_ih2, const float* __restrict__ b_hh2,
    float* __restrict__ states, float* __restrict__ bias1,
    float* __restrict__ bias2) {
  int i = blockIdx.x * 256 + threadIdx.x;
  if (i < 49152) states[i] = 0.0f;
  if (i < 1024) {
    bias1[i] = b_ih1[i] + b_hh1[i];
    bias2[i] = b_ih2[i] + b_hh2[i];
  }
}

// ---------------------------------------------------------------------------
__global__ __launch_bounds__(256) void conv_bf16_kernel(
    const float* __restrict__ in, u16* __restrict__ out, int n4) {
  int i = blockIdx.x * 256 + threadIdx.x;
  if (i < n4) {
    float4 v = *(const float4*)&in[(size_t)i * 4];
    *(ushort4*)&out[(size_t)i * 4] =
        make_ushort4(f2bf(v.x), f2bf(v.y), f2bf(v.z), f2bf(v.w));
  }
}

// w_ih2[:, 256:512] -> bf16 [1024][256]
__global__ __launch_bounds__(256) void conv_ih2r_kernel(
    const float* __restrict__ in, u16* __restrict__ out) {
  int i = (blockIdx.x * 256 + threadIdx.x) * 4;
  int row = i >> 8, k = i & 255;
  float4 v = *(const float4*)&in[(size_t)row * 512 + 256 + k];
  *(ushort4*)&out[(size_t)row * 256 + k] =
      make_ushort4(f2bf(v.x), f2bf(v.y), f2bf(v.z), f2bf(v.w));
}

// ---------------------------------------------------------------------------
// pack w_out [V=32000][H=256] f32 -> wPK bf16 MFMA-B layout:
// wPK[(((n>>4)*32 + (k>>3))*16 + (n&15))*8 + (k&7)]
__global__ __launch_bounds__(256) void pack_wout(
    const float* __restrict__ w_out, u16* __restrict__ wPK) {
  int i = blockIdx.x * 256 + threadIdx.x;  // (n, kg), i < 32000*32
  int n = i >> 5, kg = i & 31;
  float4 v0 = *(const float4*)&w_out[(size_t)n * 256 + kg * 8];
  float4 v1 = *(const float4*)&w_out[(size_t)n * 256 + kg * 8 + 4];
  size_t dst = ((size_t)((n >> 4) * 32 + kg) * 16 + (n & 15)) * 8;
  *(ushort4*)&wPK[dst] = make_ushort4(f2bf(v0.x), f2bf(v0.y), f2bf(v0.z), f2bf(v0.w));
  *(ushort4*)&wPK[dst + 4] = make_ushort4(f2bf(v1.x), f2bf(v1.y), f2bf(v1.z), f2bf(v1.w));
}

// ---------------------------------------------------------------------------
// MFMA GEMM: X1[r][n] = feat[r][:] . w_ih1b[n][:] + bias1[n]   (r=b*80+t)
#define GBM 128
#define GBN 128
#define GBK 64
#define LDST 72

__global__ __launch_bounds__(256) void gemm_x1_kernel(
    const float* __restrict__ A, const u16* __restrict__ Bw,
    const float* __restrict__ bias, float* __restrict__ C) {
  __shared__ __align__(16) u16 As[GBM * LDST];
  __shared__ __align__(16) u16 Bs[GBN * LDST];
  int tid = threadIdx.x;
  int rBase = blockIdx.y * GBM;
  int nBase = blockIdx.x * GBN;
  int lane = tid & 63, w = tid >> 6;
  int wrow = (w >> 1) * 64, wcol = (w & 1) * 64;
  int lrow = lane & 15, lk = (lane >> 4) * 8;

  f32x4 acc[4][4];
#pragma unroll
  for (int m = 0; m < 4; ++m)
#pragma unroll
    for (int n = 0; n < 4; ++n) acc[m][n] = (f32x4){0.f, 0.f, 0.f, 0.f};

  for (int k0 = 0; k0 < FEAT; k0 += GBK) {
#pragma unroll
    for (int i = 0; i < 8; ++i) {
      int f = i * 256 + tid;
      int r = f >> 4, c = (f & 15) << 2;
      float4 v = *(const float4*)&A[(size_t)(rBase + r) * FEAT + k0 + c];
      *(ushort4*)&As[r * LDST + c] =
          make_ushort4(f2bf(v.x), f2bf(v.y), f2bf(v.z), f2bf(v.w));
    }
#pragma unroll
    for (int i = 0; i < 4; ++i) {
      int f = i * 256 + tid;
      int r = f >> 3, c = (f & 7) << 3;
      uint4 v = *(const uint4*)&Bw[(size_t)(nBase + r) * FEAT + k0 + c];
      *(uint4*)&Bs[r * LDST + c] = v;
    }
    __syncthreads();
    bf16x8 af[4][2], bfr[4][2];
#pragma unroll
    for (int m = 0; m < 4; ++m)
#pragma unroll
      for (int s2 = 0; s2 < 2; ++s2)
        af[m][s2] = *(const bf16x8*)&As[(wrow + m * 16 + lrow) * LDST + s2 * 32 + lk];
#pragma unroll
    for (int n = 0; n < 4; ++n)
#pragma unroll
      for (int s2 = 0; s2 < 2; ++s2)
        bfr[n][s2] = *(const bf16x8*)&Bs[(wcol + n * 16 + lrow) * LDST + s2 * 32 + lk];
#pragma unroll
    for (int s2 = 0; s2 < 2; ++s2)
#pragma unroll
      for (int m = 0; m < 4; ++m)
#pragma unroll
        for (int n = 0; n < 4; ++n)
          acc[m][n] = __builtin_amdgcn_mfma_f32_16x16x32_bf16(
              af[m][s2], bfr[n][s2], acc[m][n], 0, 0, 0);
    __syncthreads();
  }
  int orow = (lane >> 4) * 4;
  int ocol = lane & 15;
#pragma unroll
  for (int m = 0; m < 4; ++m)
#pragma unroll
    for (int n = 0; n < 4; ++n) {
      int cidx = nBase + wcol + n * 16 + ocol;
      float bv = bias[cidx];
#pragma unroll
      for (int q = 0; q < 4; ++q) {
        int r = rBase + wrow + m * 16 + orow + q;
        C[(size_t)r * G4 + cidx] = acc[m][n][q] + bv;
      }
    }
}

// ---------------------------------------------------------------------------
// XW2[t][b][gj] = caption[b][t][:] . w_ih2[gj][0:256] + bias2[gj]
__global__ __launch_bounds__(256) void xw2_kernel(
    const float* __restrict__ caption, const float* __restrict__ w_ih2,
    const float* __restrict__ bias2, float* __restrict__ XW2) {
  int t = blockIdx.x;
  int b = blockIdx.y;
  int j = threadIdx.x;
  __shared__ float wsm[256];
  wsm[j] = caption[((size_t)b * TD + t) * W2V + j];
  __syncthreads();
  float acc0 = 0, acc1 = 0, acc2 = 0, acc3 = 0;
#pragma unroll 4
  for (int k = 0; k < 256; k++) {
    float v = wsm[k];
    acc0 += w_ih2[(j)*512 + k] * v;
    acc1 += w_ih2[(j + 256) * 512 + k] * v;
    acc2 += w_ih2[(j + 512) * 512 + k] * v;
    acc3 += w_ih2[(j + 768) * 512 + k] * v;
  }
  float* out = &XW2[((size_t)t * 32 + b) * G4];
  out[j] = acc0 + bias2[j];
  out[j + 256] = acc1 + bias2[j + 256];
  out[j + 512] = acc2 + bias2[j + 512];
  out[j + 768] = acc3 + bias2[j + 768];
}

// ---------------------------------------------------------------------------
__global__ __launch_bounds__(256) void argmax_kernel(
    const float* __restrict__ onehot, int* __restrict__ targets) {
  int s = blockIdx.x + 1;
  int b = blockIdx.y;
  int tid = threadIdx.x;
  const float* row = &onehot[((size_t)b * TD + s) * VV];
  float bv = -INFINITY;
  int bi = 0x7fffffff;
  for (int v = tid; v < VV; v += 256) {
    float x = row[v];
    if (x > bv || (x == bv && v < bi)) { bv = x; bi = v; }
  }
  __shared__ float sv[256];
  __shared__ int si[256];
  sv[tid] = bv; si[tid] = bi;
  __syncthreads();
  for (int off = 128; off; off >>= 1) {
    if (tid < off) {
      float ov = sv[tid + off]; int oi = si[tid + off];
      if (ov > sv[tid] || (ov == sv[tid] && oi < si[tid])) { sv[tid] = ov; si[tid] = oi; }
    }
    __syncthreads();
  }
  if (tid == 0) targets[blockIdx.x * 32 + b] = si[0];
}

// ===========================================================================
// Cooperative recurrent kernel
// ===========================================================================
struct Params {
  const float *X1, *XW2, *bias1, *bias2, *b_out;
  float *h1b0, *h1b1, *h2b0, *h2b1, *c1, *c2, *h2n, *encb, *logits, *loss, *out;
  u16 *h2nb;
  const u16 *w_hh1b, *w_ih2rb, *w_hh2b, *wPK;
  const int* targets;
};

#define SMEM_BYTES 43008
// smem layout for lstm: hS [32][260] f32 (33280B) | wS [16][264] u16 (8448B) | part [32][4][2] f32 (1024B)

// Block computes, for j in {j0, j0+1} and all 32 b, the 4 gate dots and state update.
__device__ __forceinline__ void lstm_block_step(
    char* smem, int j0,
    const u16* __restrict__ wA, const u16* __restrict__ wB,
    const float* __restrict__ hA, const float* __restrict__ hB,
    const float* __restrict__ xadd, int xstride,
    float* __restrict__ cst, float* __restrict__ hout,
    u16* __restrict__ houtb, float* __restrict__ enc, int enc_t) {
  float* hS = (float*)smem;                                 // [32][260]
  u16* wS = (u16*)(smem + 32 * 260 * 4);                    // [16][264]
  float* part = (float*)(smem + 32 * 260 * 4 + 16 * 264 * 2);
  int tid = threadIdx.x;
  int nmat = wB ? 2 : 1;
  // stage weights: nmat*8 rows of 256 u16 (32 uint4 chunks per row)
  for (int c = tid; c < nmat * 256; c += 256) {
    int rl = c >> 5, cc = c & 31;
    int m = rl >> 3, r = rl & 7;
    int g = r >> 1, jj = r & 1;
    const u16* src = (m ? wB : wA) + ((size_t)(g * 256 + j0 + jj)) * 256 + cc * 8;
    *(uint4*)&wS[rl * 264 + cc * 8] = *(const uint4*)src;
  }
  int b = tid >> 3, r = tid & 7;
  float acc = 0.f;
  for (int m = 0; m < nmat; ++m) {
    const float* hsrc = m ? hB : hA;
    if (m) __syncthreads();  // prior dot done before hS overwrite
    for (int c = tid; c < 2048; c += 256) {  // 32 rows x 64 float4
      int row = c >> 6, cc = c & 63;
      *(float4*)&hS[row * 260 + cc * 4] = *(const float4*)&hsrc[row * 256 + cc * 4];
    }
    __syncthreads();
    const u16* wrow = &wS[(m * 8 + r) * 264];
    const float* hrow = &hS[b * 260];
    float a = 0.f;
#pragma unroll 4
    for (int q = 0; q < 32; ++q) {
      uint4 wv = *(const uint4*)&wrow[q * 8];
      float4 x0 = *(const float4*)&hrow[q * 8];
      float4 x1 = *(const float4*)&hrow[q * 8 + 4];
      a += bflo(wv.x) * x0.x + bfhi(wv.x) * x0.y + bflo(wv.y) * x0.z + bfhi(wv.y) * x0.w +
           bflo(wv.z) * x1.x + bfhi(wv.z) * x1.y + bflo(wv.w) * x1.z + bfhi(wv.w) * x1.w;
    }
    acc += a;
  }
  int g = r >> 1, jj = r & 1;
  part[(b * 4 + g) * 2 + jj] = acc;
  __syncthreads();
  if (tid < 64) {
    int b2 = tid >> 1, jj2 = tid & 1;
    int j = j0 + jj2;
    const float* xa = xadd + (size_t)b2 * xstride;
    float gi = part[(b2 * 4 + 0) * 2 + jj2] + xa[j];
    float gf = part[(b2 * 4 + 1) * 2 + jj2] + xa[256 + j];
    float gg = part[(b2 * 4 + 2) * 2 + jj2] + xa[512 + j];
    float go = part[(b2 * 4 + 3) * 2 + jj2] + xa[768 + j];
    int idx = b2 * 256 + j;
    float c = sigm(gf) * cst[idx] + sigm(gi) * tanhf(gg);
    float h = sigm(go) * tanhf(c);
    cst[idx] = c;
    hout[idx] = h;
    if (houtb) houtb[idx] = f2bf(h);
    if (enc) enc[((size_t)b2 * TE + enc_t) * 256 + j] = h;
  }
}

// logits tiles for this block: [t0,t1) n-tiles of 16, MFMA 16x16x32, K=256
__device__ __forceinline__ void logits_block(
    char* smem, int bid, const u16* __restrict__ h2nb, const u16* __restrict__ wPK,
    const float* __restrict__ b_out, float* __restrict__ logits) {
  u16* aS = (u16*)smem;  // [32][264]
  int tid = threadIdx.x;
  for (int c = tid; c < 1024; c += 256) {
    int row = c >> 5, cc = c & 31;
    *(uint4*)&aS[row * 264 + cc * 8] = *(const uint4*)&h2nb[row * 256 + cc * 8];
  }
  __syncthreads();
  int wid = tid >> 6, lane = tid & 63;
  int lcol = lane & 15, lk = lane >> 4;
  int t0 = (bid * 2000) / 224, t1 = ((bid + 1) * 2000) / 224;
  for (int nt = t0 + wid; nt < t1; nt += 4) {
    f32x4 acc0 = {0.f, 0.f, 0.f, 0.f}, acc1 = {0.f, 0.f, 0.f, 0.f};
#pragma unroll
    for (int ks = 0; ks < 8; ++ks) {
      bf16x8 a0 = *(const bf16x8*)&aS[lcol * 264 + ks * 32 + lk * 8];
      bf16x8 a1 = *(const bf16x8*)&aS[(16 + lcol) * 264 + ks * 32 + lk * 8];
      bf16x8 bf = *(const bf16x8*)&wPK[((size_t)(nt * 32 + ks * 4 + lk) * 16 + lcol) * 8];
      acc0 = __builtin_amdgcn_mfma_f32_16x16x32_bf16(a0, bf, acc0, 0, 0, 0);
      acc1 = __builtin_amdgcn_mfma_f32_16x16x32_bf16(a1, bf, acc1, 0, 0, 0);
    }
    int n = nt * 16 + lcol;
    float bo = b_out[n];
#pragma unroll
    for (int q = 0; q < 4; ++q) {
      int r0 = lk * 4 + q;
      logits[(size_t)r0 * VV + n] = acc0[q] + bo;
      logits[(size_t)(16 + r0) * VV + n] = acc1[q] + bo;
    }
  }
}

__device__ __forceinline__ void ce_block(
    char* smem, int b, const float* __restrict__ logits,
    const int* __restrict__ tgtp, float* __restrict__ loss) {
  float* sm = (float*)smem;
  int tid = threadIdx.x;
  const float* row = &logits[(size_t)b * VV];
  float m = -INFINITY;
  for (int v = tid; v < VV; v += 256) m = fmaxf(m, row[v]);
  sm[tid] = m;
  __syncthreads();
  for (int off = 128; off; off >>= 1) {
    if (tid < off) sm[tid] = fmaxf(sm[tid], sm[tid + off]);
    __syncthreads();
  }
  m = sm[0];
  __syncthreads();
  float s = 0;
  for (int v = tid; v < VV; v += 256) s += expf(row[v] - m);
  sm[tid] = s;
  __syncthreads();
  for (int off = 128; off; off >>= 1) {
    if (tid < off) sm[tid] += sm[tid + off];
    __syncthreads();
  }
  if (tid == 0) {
    atomicAdd(loss, (m + logf(sm[0]) - row[*tgtp]) * (1.0f / 1024.0f));
  }
}

__device__ __forceinline__ void attn_block(
    char* smem, int b, const float* __restrict__ enc,
    const float* __restrict__ h2n, float* __restrict__ hout) {
  float* q = (float*)smem;
  float* sc = q + 256;
  float* ms = sc + 80;
  int tid = threadIdx.x;
  q[tid] = h2n[b * 256 + tid];
  __syncthreads();
  if (tid < 80) {
    const float* e = &enc[((size_t)b * TE + tid) * 256];
    float a = 0;
#pragma unroll 8
    for (int k = 0; k < 256; k++) a += e[k] * q[k];
    sc[tid] = a;
  }
  __syncthreads();
  if (tid == 0) {
    float m = -INFINITY;
    for (int t = 0; t < 80; t++) m = fmaxf(m, sc[t]);
    float s = 0;
    for (int t = 0; t < 80; t++) s += expf(sc[t] - m);
    ms[0] = m;
    ms[1] = 1.0f / s;
  }
  __syncthreads();
  if (tid < 80) sc[tid] = expf(sc[tid] - ms[0]) * ms[1];
  __syncthreads();
  float a = 0;
#pragma unroll 8
  for (int t = 0; t < 80; t++) a += sc[t] * enc[((size_t)b * TE + t) * 256 + tid];
  hout[b * 256 + tid] = a;
}

__global__ __launch_bounds__(256, 1) void recurrent_kernel(Params p) {
  cg::grid_group grid = cg::this_grid();
  __shared__ __align__(16) char smem[SMEM_BYTES];
  int bid = blockIdx.x;
  float* h1b[2] = {p.h1b0, p.h1b1};
  float* h2b[2] = {p.h2b0, p.h2b1};

  // -------- encoder: pipelined, 81 iterations --------
  for (int it = 0; it <= TE; ++it) {
    if (bid < 128) {
      if (it < TE)
        lstm_block_step(smem, bid * 2, p.w_hh1b, nullptr, h1b[it & 1], nullptr,
                        p.X1 + (size_t)it * G4, TE * G4, p.c1, h1b[(it + 1) & 1],
                        nullptr, nullptr, 0);
    } else {
      if (it == 0 && bid == 128 && threadIdx.x == 0) p.loss[0] = 0.f;
      if (it >= 1)
        lstm_block_step(smem, (bid - 128) * 2, p.w_ih2rb, p.w_hh2b, h1b[it & 1],
                        h2b[(it - 1) & 1], p.bias2, 0, p.c2, h2b[it & 1],
                        nullptr, p.encb, it - 1);
    }
    grid.sync();
  }
  // H1[80] in h1b[0], H2[80] in h2b[0]

  // -------- decoder: 29 steps, 3 phases each --------
  for (int s = 0; s < TD - 1; ++s) {
    // P1: lstm1 (blocks 0..127) || ce of step s-1 (blocks 128..159)
    if (bid < 128) {
      lstm_block_step(smem, bid * 2, p.w_hh1b, nullptr, h1b[s & 1], nullptr,
                      p.bias1, 0, p.c1, h1b[(s + 1) & 1], nullptr, nullptr, 0);
    } else if (bid < 160 && s >= 1) {
      ce_block(smem, bid - 128, p.logits, p.targets + (s - 1) * 32 + (bid - 128), p.loss);
    }
    grid.sync();
    // P2: lstm2 -> h2n (f32 + bf16)
    if (bid < 128) {
      lstm_block_step(smem, bid * 2, p.w_ih2rb, p.w_hh2b, h1b[(s + 1) & 1], h2b[s & 1],
                      p.XW2 + (size_t)s * 32 * G4, G4, p.c2, p.h2n, p.h2nb, nullptr, 0);
    }
    grid.sync();
    // P3: logits MFMA (blocks 0..223) || attention (blocks 224..255)
    if (bid < 224) {
      logits_block(smem, bid, p.h2nb, p.wPK, p.b_out, p.logits);
    } else {
      attn_block(smem, bid - 224, p.encb, p.h2n, h2b[(s + 1) & 1]);
    }
    grid.sync();
  }
  // final ce for s=28
  if (bid < 32) ce_block(smem, bid, p.logits, p.targets + 28 * 32 + bid, p.loss);
  grid.sync();
  if (bid == 0 && threadIdx.x == 0) p.out[0] = p.loss[0];
}

// ---------------------------------------------------------------------------
extern "C" void kernel_launch(void* const* d_in, const int* in_sizes, int n_in,
                              void* d_out, int out_size, void* d_ws, size_t ws_size,
                              hipStream_t stream) {
  (void)in_sizes; (void)n_in; (void)out_size; (void)ws_size;
  const float* feat    = (const float*)d_in[0];
  const float* caption = (const float*)d_in[1];
  const float* onehot  = (const float*)d_in[2];
  const float* w_ih1   = (const float*)d_in[4];
  const float* w_hh1   = (const float*)d_in[5];
  const float* b_ih1   = (const float*)d_in[6];
  const float* b_hh1   = (const float*)d_in[7];
  const float* w_ih2   = (const float*)d_in[8];
  const float* w_hh2   = (const float*)d_in[9];
  const float* b_ih2   = (const float*)d_in[10];
  const float* b_hh2   = (const float*)d_in[11];
  const float* w_out   = (const float*)d_in[12];
  const float* b_out   = (const float*)d_in[13];

  char* p = (char*)d_ws;
  auto alloc = [&](size_t bytes) {
    char* r = p;
    p += (bytes + 255) & ~(size_t)255;
    return r;
  };
  float* X1      = (float*)alloc(2560ull * 1024 * 4);
  float* XW2     = (float*)alloc(29ull * 32 * 1024 * 4);
  float* bias1   = (float*)alloc(1024 * 4);
  float* bias2   = (float*)alloc(1024 * 4);
  float* st      = (float*)alloc(6ull * 8192 * 4);
  float* h2n     = (float*)alloc(8192 * 4);
  u16*   h2nb    = (u16*)alloc(8192 * 2);
  float* encb    = (float*)alloc(32ull * 80 * 256 * 4);
  float* logits  = (float*)alloc(32ull * VV * 4);
  float* lossacc = (float*)alloc(256);
  int*   targets = (int*)alloc(29 * 32 * 4);
  u16*   w_ih1b  = (u16*)alloc(1024ull * 4096 * 2);
  u16*   w_hh1b  = (u16*)alloc(1024ull * 256 * 2);
  u16*   w_ih2rb = (u16*)alloc(1024ull * 256 * 2);
  u16*   w_hh2b  = (u16*)alloc(1024ull * 256 * 2);
  u16*   wPK     = (u16*)alloc(2000ull * 32 * 16 * 8 * 2);

  float* h1b0 = st, *h1b1 = st + 8192, *h2b0 = st + 16384, *h2b1 = st + 24576;
  float* c1 = st + 32768, *c2 = st + 40960;

  init_kernel<<<192, 256, 0, stream>>>(b_ih1, b_hh1, b_ih2, b_hh2, st, bias1, bias2);
  conv_bf16_kernel<<<4096, 256, 0, stream>>>(w_ih1, w_ih1b, 1048576);
  conv_bf16_kernel<<<256, 256, 0, stream>>>(w_hh1, w_hh1b, 65536);
  conv_bf16_kernel<<<256, 256, 0, stream>>>(w_hh2, w_hh2b, 65536);
  conv_ih2r_kernel<<<256, 256, 0, stream>>>(w_ih2, w_ih2rb);
  pack_wout<<<4000, 256, 0, stream>>>(w_out, wPK);
  gemm_x1_kernel<<<dim3(8, 20), 256, 0, stream>>>(feat, w_ih1b, bias1, X1);
  xw2_kernel<<<dim3(29, 32), 256, 0, stream>>>(caption, w_ih2, bias2, XW2);
  argmax_kernel<<<dim3(29, 32), 256, 0, stream>>>(onehot, targets);

  Params prm;
  prm.X1 = X1; prm.XW2 = XW2; prm.bias1 = bias1; prm.bias2 = bias2; prm.b_out = b_out;
  prm.h1b0 = h1b0; prm.h1b1 = h1b1; prm.h2b0 = h2b0; prm.h2b1 = h2b1;
  prm.c1 = c1; prm.c2 = c2; prm.h2n = h2n; prm.encb = encb; prm.logits = logits;
  prm.loss = lossacc; prm.out = (float*)d_out; prm.h2nb = h2nb;
  prm.w_hh1b = w_hh1b; prm.w_ih2rb = w_ih2rb; prm.w_hh2b = w_hh2b; prm.wPK = wPK;
  prm.targets = targets;
  void* args[] = {&prm};
  hipLaunchCooperativeKernel((const void*)recurrent_kernel, dim3(256), dim3(256),
                             args, 0, stream);
}

// Round 4
// 2154.966 us; speedup vs baseline: 3.5809x; 3.5809x over previous
//
#include <hip/hip_runtime.h>
#include <hip/hip_bf16.h>
#include <math.h>

// Problem dims
#define BB 32
#define TE 80
#define FEAT 4096
#define HH 256
#define W2V 256
#define TD 30
#define VV 32000
#define G4 1024   // 4*H

typedef unsigned short u16;
typedef unsigned int u32;
using f32x4 = __attribute__((ext_vector_type(4))) float;
using bf16x8 = __attribute__((ext_vector_type(8))) short;

__device__ __forceinline__ float sigm(float x) { return 1.0f / (1.0f + expf(-x)); }
__device__ __forceinline__ u16 f2bf(float f) {
  u32 u = __float_as_uint(f);
  u32 r = (u + 0x7FFFu + ((u >> 16) & 1u)) >> 16;
  return (u16)r;
}
__device__ __forceinline__ float bflo(u32 p) { return __uint_as_float(p << 16); }
__device__ __forceinline__ float bfhi(u32 p) { return __uint_as_float(p & 0xFFFF0000u); }

// ---------------------------------------------------------------------------
// init: zero states (h1b0,h1b1,h2b0,h2b1,c1,c2); loss; bias sums
__global__ __launch_bounds__(256) void init_kernel(
    const float* __restrict__ b_ih1, const float* __restrict__ b_hh1,
    const float* __restrict__ b_ih2, const float* __restrict__ b_hh2,
    float* __restrict__ states, float* __restrict__ bias1,
    float* __restrict__ bias2, float* __restrict__ loss) {
  int i = blockIdx.x * 256 + threadIdx.x;
  if (i < 49152) states[i] = 0.0f;
  if (i < 1024) {
    bias1[i] = b_ih1[i] + b_hh1[i];
    bias2[i] = b_ih2[i] + b_hh2[i];
  }
  if (i == 0) *loss = 0.0f;
}

// ---------------------------------------------------------------------------
__global__ __launch_bounds__(256) void conv_bf16_kernel(
    const float* __restrict__ in, u16* __restrict__ out, int n4) {
  int i = blockIdx.x * 256 + threadIdx.x;
  if (i < n4) {
    float4 v = *(const float4*)&in[(size_t)i * 4];
    *(ushort4*)&out[(size_t)i * 4] =
        make_ushort4(f2bf(v.x), f2bf(v.y), f2bf(v.z), f2bf(v.w));
  }
}

// w_ih2[:, 256:512] -> bf16 [1024][256]
__global__ __launch_bounds__(256) void conv_ih2r_kernel(
    const float* __restrict__ in, u16* __restrict__ out) {
  int i = (blockIdx.x * 256 + threadIdx.x) * 4;
  int row = i >> 8, k = i & 255;
  float4 v = *(const float4*)&in[(size_t)row * 512 + 256 + k];
  *(ushort4*)&out[(size_t)row * 256 + k] =
      make_ushort4(f2bf(v.x), f2bf(v.y), f2bf(v.z), f2bf(v.w));
}

// ---------------------------------------------------------------------------
// pack w_out [V=32000][H=256] f32 -> wPK bf16 MFMA-B layout:
// wPK[(((n>>4)*32 + (k>>3))*16 + (n&15))*8 + (k&7)]
__global__ __launch_bounds__(256) void pack_wout(
    const float* __restrict__ w_out, u16* __restrict__ wPK) {
  int i = blockIdx.x * 256 + threadIdx.x;  // (n, kg), i < 32000*32
  int n = i >> 5, kg = i & 31;
  float4 v0 = *(const float4*)&w_out[(size_t)n * 256 + kg * 8];
  float4 v1 = *(const float4*)&w_out[(size_t)n * 256 + kg * 8 + 4];
  size_t dst = ((size_t)((n >> 4) * 32 + kg) * 16 + (n & 15)) * 8;
  *(ushort4*)&wPK[dst] = make_ushort4(f2bf(v0.x), f2bf(v0.y), f2bf(v0.z), f2bf(v0.w));
  *(ushort4*)&wPK[dst + 4] = make_ushort4(f2bf(v1.x), f2bf(v1.y), f2bf(v1.z), f2bf(v1.w));
}

// ---------------------------------------------------------------------------
// MFMA GEMM: X1[r][n] = feat[r][:] . w_ih1b[n][:] + bias1[n]   (r = b*80+t)
#define GBM 128
#define GBN 128
#define GBK 64
#define LDST 72

__global__ __launch_bounds__(256) void gemm_x1_kernel(
    const float* __restrict__ A, const u16* __restrict__ Bw,
    const float* __restrict__ bias, float* __restrict__ C) {
  __shared__ __align__(16) u16 As[GBM * LDST];
  __shared__ __align__(16) u16 Bs[GBN * LDST];
  int tid = threadIdx.x;
  int rBase = blockIdx.y * GBM;
  int nBase = blockIdx.x * GBN;
  int lane = tid & 63, w = tid >> 6;
  int wrow = (w >> 1) * 64, wcol = (w & 1) * 64;
  int lrow = lane & 15, lk = (lane >> 4) * 8;

  f32x4 acc[4][4];
#pragma unroll
  for (int m = 0; m < 4; ++m)
#pragma unroll
    for (int n = 0; n < 4; ++n) acc[m][n] = (f32x4){0.f, 0.f, 0.f, 0.f};

  for (int k0 = 0; k0 < FEAT; k0 += GBK) {
#pragma unroll
    for (int i = 0; i < 8; ++i) {
      int f = i * 256 + tid;
      int r = f >> 4, c = (f & 15) << 2;
      float4 v = *(const float4*)&A[(size_t)(rBase + r) * FEAT + k0 + c];
      *(ushort4*)&As[r * LDST + c] =
          make_ushort4(f2bf(v.x), f2bf(v.y), f2bf(v.z), f2bf(v.w));
    }
#pragma unroll
    for (int i = 0; i < 4; ++i) {
      int f = i * 256 + tid;
      int r = f >> 3, c = (f & 7) << 3;
      uint4 v = *(const uint4*)&Bw[(size_t)(nBase + r) * FEAT + k0 + c];
      *(uint4*)&Bs[r * LDST + c] = v;
    }
    __syncthreads();
    bf16x8 af[4][2], bfr[4][2];
#pragma unroll
    for (int m = 0; m < 4; ++m)
#pragma unroll
      for (int s2 = 0; s2 < 2; ++s2)
        af[m][s2] = *(const bf16x8*)&As[(wrow + m * 16 + lrow) * LDST + s2 * 32 + lk];
#pragma unroll
    for (int n = 0; n < 4; ++n)
#pragma unroll
      for (int s2 = 0; s2 < 2; ++s2)
        bfr[n][s2] = *(const bf16x8*)&Bs[(wcol + n * 16 + lrow) * LDST + s2 * 32 + lk];
#pragma unroll
    for (int s2 = 0; s2 < 2; ++s2)
#pragma unroll
      for (int m = 0; m < 4; ++m)
#pragma unroll
        for (int n = 0; n < 4; ++n)
          acc[m][n] = __builtin_amdgcn_mfma_f32_16x16x32_bf16(
              af[m][s2], bfr[n][s2], acc[m][n], 0, 0, 0);
    __syncthreads();
  }
  int orow = (lane >> 4) * 4;
  int ocol = lane & 15;
#pragma unroll
  for (int m = 0; m < 4; ++m)
#pragma unroll
    for (int n = 0; n < 4; ++n) {
      int cidx = nBase + wcol + n * 16 + ocol;
      float bv = bias[cidx];
#pragma unroll
      for (int q = 0; q < 4; ++q) {
        int r = rBase + wrow + m * 16 + orow + q;
        C[(size_t)r * G4 + cidx] = acc[m][n][q] + bv;
      }
    }
}

// ---------------------------------------------------------------------------
// XW2[t][b][gj] = caption[b][t][:] . w_ih2[gj][0:256] + bias2[gj]
__global__ __launch_bounds__(256) void xw2_kernel(
    const float* __restrict__ caption, const float* __restrict__ w_ih2,
    const float* __restrict__ bias2, float* __restrict__ XW2) {
  int t = blockIdx.x;
  int b = blockIdx.y;
  int j = threadIdx.x;
  __shared__ float wsm[256];
  wsm[j] = caption[((size_t)b * TD + t) * W2V + j];
  __syncthreads();
  float acc0 = 0, acc1 = 0, acc2 = 0, acc3 = 0;
#pragma unroll 4
  for (int k = 0; k < 256; k++) {
    float v = wsm[k];
    acc0 += w_ih2[(j)*512 + k] * v;
    acc1 += w_ih2[(j + 256) * 512 + k] * v;
    acc2 += w_ih2[(j + 512) * 512 + k] * v;
    acc3 += w_ih2[(j + 768) * 512 + k] * v;
  }
  float* out = &XW2[((size_t)t * 32 + b) * G4];
  out[j] = acc0 + bias2[j];
  out[j + 256] = acc1 + bias2[j + 256];
  out[j + 512] = acc2 + bias2[j + 512];
  out[j + 768] = acc3 + bias2[j + 768];
}

// ---------------------------------------------------------------------------
__global__ __launch_bounds__(256) void argmax_kernel(
    const float* __restrict__ onehot, int* __restrict__ targets) {
  int s = blockIdx.x + 1;
  int b = blockIdx.y;
  int tid = threadIdx.x;
  const float* row = &onehot[((size_t)b * TD + s) * VV];
  float bv = -INFINITY;
  int bi = 0x7fffffff;
  for (int v = tid; v < VV; v += 256) {
    float x = row[v];
    if (x > bv || (x == bv && v < bi)) { bv = x; bi = v; }
  }
  __shared__ float sv[256];
  __shared__ int si[256];
  sv[tid] = bv; si[tid] = bi;
  __syncthreads();
  for (int off = 128; off; off >>= 1) {
    if (tid < off) {
      float ov = sv[tid + off]; int oi = si[tid + off];
      if (ov > sv[tid] || (ov == sv[tid] && oi < si[tid])) { sv[tid] = ov; si[tid] = oi; }
    }
    __syncthreads();
  }
  if (tid == 0) targets[blockIdx.x * 32 + b] = si[0];
}

// ===========================================================================
// Recurrent step kernels (multi-launch, pipeline-fused roles)
// ===========================================================================
struct StepP {
  const float *X1, *XW2, *bias1, *bias2;
  float *h1b0, *h1b1, *h2b0, *h2b1, *c1, *c2, *h2nf, *encb;
  u16* H2NB;
  const u16 *w_hh1b, *w_ih2rb, *w_hh2b;
};

// bid in [0,128): jq = bid&3, b = bid>>2; thread = (g, jj) row dot over 256.
__device__ __forceinline__ void lstm1_body(
    int bid, float* hs, float (*gsm)[64],
    const float* __restrict__ xadd, int xstride,
    const float* __restrict__ h1in, float* __restrict__ h1out,
    float* __restrict__ c1, const u16* __restrict__ w) {
  int jq = bid & 3, b = bid >> 2;
  int tid = threadIdx.x;
  int g = tid >> 6, jj = tid & 63;
  int j = (jq << 6) + jj;
  int row = (g << 8) + j;
  hs[tid] = h1in[(b << 8) + tid];
  __syncthreads();
  const uint4* wv = (const uint4*)(w + (size_t)row * 256);
  const float4* hv = (const float4*)hs;
  float acc = 0.f;
#pragma unroll 4
  for (int q = 0; q < 32; ++q) {
    uint4 a = wv[q];
    float4 x0 = hv[2 * q], x1 = hv[2 * q + 1];
    acc += bflo(a.x) * x0.x + bfhi(a.x) * x0.y + bflo(a.y) * x0.z + bfhi(a.y) * x0.w +
           bflo(a.z) * x1.x + bfhi(a.z) * x1.y + bflo(a.w) * x1.z + bfhi(a.w) * x1.w;
  }
  if (g) gsm[g - 1][jj] = acc;
  __syncthreads();
  if (g == 0) {
    const float* xa = xadd + (size_t)b * xstride;
    float gi = acc + xa[j];
    float gf = gsm[0][jj] + xa[256 + j];
    float gg = gsm[1][jj] + xa[512 + j];
    float go = gsm[2][jj] + xa[768 + j];
    int idx = (b << 8) + j;
    float c = sigm(gf) * c1[idx] + sigm(gi) * tanhf(gg);
    float h = sigm(go) * tanhf(c);
    c1[idx] = c;
    h1out[idx] = h;
  }
}

__device__ __forceinline__ void lstm2_body(
    int bid, float* h1s, float* h2s, float (*gsm)[64],
    const float* __restrict__ xadd, int xstride,
    const float* __restrict__ h1, const float* __restrict__ h2in,
    float* __restrict__ h2out, float* __restrict__ c2,
    const u16* __restrict__ wih2r, const u16* __restrict__ whh2,
    float* __restrict__ enc, int enc_t, u16* __restrict__ h2nb) {
  int jq = bid & 3, b = bid >> 2;
  int tid = threadIdx.x;
  int g = tid >> 6, jj = tid & 63;
  int j = (jq << 6) + jj;
  int row = (g << 8) + j;
  h1s[tid] = h1[(b << 8) + tid];
  h2s[tid] = h2in[(b << 8) + tid];
  __syncthreads();
  const uint4* w1 = (const uint4*)(wih2r + (size_t)row * 256);
  const uint4* w2 = (const uint4*)(whh2 + (size_t)row * 256);
  const float4* hv1 = (const float4*)h1s;
  const float4* hv2 = (const float4*)h2s;
  float acc = 0.f;
#pragma unroll 4
  for (int q = 0; q < 32; ++q) {
    uint4 a = w1[q];
    float4 x0 = hv1[2 * q], x1 = hv1[2 * q + 1];
    acc += bflo(a.x) * x0.x + bfhi(a.x) * x0.y + bflo(a.y) * x0.z + bfhi(a.y) * x0.w +
           bflo(a.z) * x1.x + bfhi(a.z) * x1.y + bflo(a.w) * x1.z + bfhi(a.w) * x1.w;
  }
#pragma unroll 4
  for (int q = 0; q < 32; ++q) {
    uint4 a = w2[q];
    float4 x0 = hv2[2 * q], x1 = hv2[2 * q + 1];
    acc += bflo(a.x) * x0.x + bfhi(a.x) * x0.y + bflo(a.y) * x0.z + bfhi(a.y) * x0.w +
           bflo(a.z) * x1.x + bfhi(a.z) * x1.y + bflo(a.w) * x1.z + bfhi(a.w) * x1.w;
  }
  if (g) gsm[g - 1][jj] = acc;
  __syncthreads();
  if (g == 0) {
    const float* xa = xadd + (size_t)b * xstride;
    float gi = acc + xa[j];
    float gf = gsm[0][jj] + xa[256 + j];
    float gg = gsm[1][jj] + xa[512 + j];
    float go = gsm[2][jj] + xa[768 + j];
    int idx = (b << 8) + j;
    float c = sigm(gf) * c2[idx] + sigm(gi) * tanhf(gg);
    float h = sigm(go) * tanhf(c);
    c2[idx] = c;
    h2out[idx] = h;
    if (h2nb) h2nb[idx] = f2bf(h);
    if (enc) enc[((size_t)b * TE + enc_t) * 256 + j] = h;
  }
}

// Encoder launch t in [0,80]: blocks 0-127 = lstm1(t) (t<80) or dec-lstm1(0)
// (t==80); blocks 128-255 = enc-lstm2(t-1) (t>=1).
__global__ __launch_bounds__(256) void step_enc(StepP p, int t) {
  __shared__ __align__(16) float h1s[256], h2s[256];
  __shared__ float gsm[3][64];
  int bid = blockIdx.x;
  float* h1b[2] = {p.h1b0, p.h1b1};
  float* h2b[2] = {p.h2b0, p.h2b1};
  if (bid < 128) {
    if (t < TE)
      lstm1_body(bid, h1s, gsm, p.X1 + (size_t)t * G4, TE * G4,
                 h1b[t & 1], h1b[(t + 1) & 1], p.c1, p.w_hh1b);
    else
      lstm1_body(bid, h1s, gsm, p.bias1, 0, h1b[0], h1b[1], p.c1, p.w_hh1b);
  } else if (t >= 1) {
    lstm2_body(bid - 128, h1s, h2s, gsm, p.bias2, 0, h1b[t & 1], h2b[t & 1],
               h2b[(t + 1) & 1], p.c2, p.w_ih2rb, p.w_hh2b, p.encb, t - 1, nullptr);
  }
}

// Decoder launch D1(s): blocks 0-127 = lstm2(s) -> h2nf + H2NB[s];
// blocks 128-255 = lstm1(s+1) (s<28).
__global__ __launch_bounds__(256) void step_dec1(StepP p, int s) {
  __shared__ __align__(16) float h1s[256], h2s[256];
  __shared__ float gsm[3][64];
  int bid = blockIdx.x;
  float* h1b[2] = {p.h1b0, p.h1b1};
  float* h2b[2] = {p.h2b0, p.h2b1};
  if (bid < 128) {
    lstm2_body(bid, h1s, h2s, gsm, p.XW2 + (size_t)s * 32 * G4, G4,
               h1b[(s + 1) & 1], h2b[(s + 1) & 1], p.h2nf, p.c2,
               p.w_ih2rb, p.w_hh2b, nullptr, 0, p.H2NB + (size_t)s * 8192);
  } else if (s < TD - 2) {
    lstm1_body(bid - 128, h1s, gsm, p.bias1, 0, h1b[(s + 1) & 1], h1b[s & 1],
               p.c1, p.w_hh1b);
  }
}

// Decoder launch D2(s): attention -> h2b[s&1]
__global__ __launch_bounds__(256) void step_dec2(StepP p, int s) {
  __shared__ float q[256];
  __shared__ float sc[80];
  __shared__ float ms[2];
  int b = blockIdx.x;
  int tid = threadIdx.x;
  float* h2b[2] = {p.h2b0, p.h2b1};
  float* hout = h2b[s & 1];
  q[tid] = p.h2nf[b * 256 + tid];
  __syncthreads();
  if (tid < 80) {
    const float* e = &p.encb[((size_t)b * TE + tid) * 256];
    float a = 0;
#pragma unroll 8
    for (int k = 0; k < 256; k++) a += e[k] * q[k];
    sc[tid] = a;
  }
  __syncthreads();
  if (tid == 0) {
    float m = -INFINITY;
    for (int t = 0; t < 80; t++) m = fmaxf(m, sc[t]);
    float s2 = 0;
    for (int t = 0; t < 80; t++) s2 += expf(sc[t] - m);
    ms[0] = m;
    ms[1] = 1.0f / s2;
  }
  __syncthreads();
  if (tid < 80) sc[tid] = expf(sc[tid] - ms[0]) * ms[1];
  __syncthreads();
  float a = 0;
#pragma unroll 8
  for (int t = 0; t < 80; t++) a += sc[t] * p.encb[((size_t)b * TE + t) * 256 + tid];
  hout[b * 256 + tid] = a;
}

// ===========================================================================
// Batched logits + fused CE partials: M=928 (29 steps x 32 batch), N=32000,
// K=256. 250 blocks x 128 cols. Per rowgroup (32 rows): MFMA then per-row
// (max, sumexp) partials per 32-col chunk; tgt logit captured.
// ===========================================================================
__global__ __launch_bounds__(256, 1) void logits_ce_kernel(
    const u16* __restrict__ H2NB, const u16* __restrict__ wPK,
    const float* __restrict__ b_out, const int* __restrict__ targets,
    float* __restrict__ pmaxA, float* __restrict__ psumA,
    float* __restrict__ tgtv) {
  __shared__ __align__(16) u16 bS[32768];  // 8 n-tiles x 32 kg x 16 x 8
  __shared__ __align__(16) u16 aS[32 * 264];
  __shared__ int tS[32];
  int tid = threadIdx.x, bid = blockIdx.x;
  const u16* src = wPK + (size_t)bid * 32768;
  for (int i = tid; i < 4096; i += 256)
    *(uint4*)&bS[i * 8] = *(const uint4*)&src[i * 8];
  int wid = tid >> 6, lane = tid & 63, lcol = lane & 15, lk = lane >> 4;
  float bo[2];
#pragma unroll
  for (int n = 0; n < 2; ++n) bo[n] = b_out[(bid * 8 + wid * 2 + n) * 16 + lcol];

  for (int rg = 0; rg < 29; ++rg) {
    __syncthreads();
    for (int i = tid; i < 1024; i += 256) {
      int row = i >> 5, cc = i & 31;
      *(uint4*)&aS[row * 264 + cc * 8] =
          *(const uint4*)&H2NB[(size_t)rg * 8192 + row * 256 + cc * 8];
    }
    if (tid < 32) tS[tid] = targets[rg * 32 + tid];
    __syncthreads();
    f32x4 acc[2][2];
#pragma unroll
    for (int m = 0; m < 2; ++m)
#pragma unroll
      for (int n = 0; n < 2; ++n) acc[m][n] = (f32x4){0.f, 0.f, 0.f, 0.f};
#pragma unroll
    for (int ks = 0; ks < 8; ++ks) {
      bf16x8 a0 = *(const bf16x8*)&aS[lcol * 264 + ks * 32 + lk * 8];
      bf16x8 a1 = *(const bf16x8*)&aS[(16 + lcol) * 264 + ks * 32 + lk * 8];
      bf16x8 b0 = *(const bf16x8*)&bS[(wid * 2) * 4096 + ((ks * 4 + lk) * 16 + lcol) * 8];
      bf16x8 b1 = *(const bf16x8*)&bS[(wid * 2 + 1) * 4096 + ((ks * 4 + lk) * 16 + lcol) * 8];
      acc[0][0] = __builtin_amdgcn_mfma_f32_16x16x32_bf16(a0, b0, acc[0][0], 0, 0, 0);
      acc[0][1] = __builtin_amdgcn_mfma_f32_16x16x32_bf16(a0, b1, acc[0][1], 0, 0, 0);
      acc[1][0] = __builtin_amdgcn_mfma_f32_16x16x32_bf16(a1, b0, acc[1][0], 0, 0, 0);
      acc[1][1] = __builtin_amdgcn_mfma_f32_16x16x32_bf16(a1, b1, acc[1][1], 0, 0, 0);
    }
    int nbase = (bid * 8 + wid * 2) * 16 + lcol;
#pragma unroll
    for (int m = 0; m < 2; ++m) {
      float pm[4], ps[4];
#pragma unroll
      for (int q = 0; q < 4; ++q) {
        float v0 = acc[m][0][q] + bo[0];
        float v1 = acc[m][1][q] + bo[1];
        int r = m * 16 + lk * 4 + q;
        int tg = tS[r];
        if (tg == nbase) tgtv[rg * 32 + r] = v0;
        if (tg == nbase + 16) tgtv[rg * 32 + r] = v1;
        float mx = fmaxf(v0, v1);
#pragma unroll
        for (int d = 1; d < 16; d <<= 1) mx = fmaxf(mx, __shfl_xor(mx, d));
        float e = expf(v0 - mx) + expf(v1 - mx);
#pragma unroll
        for (int d = 1; d < 16; d <<= 1) e += __shfl_xor(e, d);
        pm[q] = mx;
        ps[q] = e;
      }
      if (lcol == 0) {
        int chunk = bid * 4 + wid;  // 0..999
#pragma unroll
        for (int q = 0; q < 4; ++q) {
          int row = rg * 32 + m * 16 + lk * 4 + q;
          pmaxA[(size_t)row * 1000 + chunk] = pm[q];
          psumA[(size_t)row * 1000 + chunk] = ps[q];
        }
      }
    }
  }
}

// loss = sum_rows (log(sum_c psum*exp(pmax-M)) + M - tgtv) / 1024
__global__ __launch_bounds__(256) void ce_final_kernel(
    const float* __restrict__ pmaxA, const float* __restrict__ psumA,
    const float* __restrict__ tgtv, float* __restrict__ loss) {
  int row = blockIdx.x * 256 + threadIdx.x;
  float contrib = 0.f;
  if (row < 928) {
    const float* pm = pmaxA + (size_t)row * 1000;
    const float* ps = psumA + (size_t)row * 1000;
    float M = -INFINITY;
    for (int c = 0; c < 1000; ++c) M = fmaxf(M, pm[c]);
    float S = 0.f;
    for (int c = 0; c < 1000; ++c) S += ps[c] * expf(pm[c] - M);
    contrib = (M + logf(S) - tgtv[row]) * (1.0f / 1024.0f);
  }
  __shared__ float sm[256];
  sm[threadIdx.x] = contrib;
  __syncthreads();
  for (int off = 128; off; off >>= 1) {
    if (threadIdx.x < off) sm[threadIdx.x] += sm[threadIdx.x + off];
    __syncthreads();
  }
  if (threadIdx.x == 0) atomicAdd(loss, sm[0]);
}

__global__ void finalize_kernel(const float* __restrict__ loss, float* __restrict__ out) {
  if (threadIdx.x == 0) out[0] = loss[0];
}

// ---------------------------------------------------------------------------
extern "C" void kernel_launch(void* const* d_in, const int* in_sizes, int n_in,
                              void* d_out, int out_size, void* d_ws, size_t ws_size,
                              hipStream_t stream) {
  (void)in_sizes; (void)n_in; (void)out_size; (void)ws_size;
  const float* feat    = (const float*)d_in[0];
  const float* caption = (const float*)d_in[1];
  const float* onehot  = (const float*)d_in[2];
  const float* w_ih1   = (const float*)d_in[4];
  const float* w_hh1   = (const float*)d_in[5];
  const float* b_ih1   = (const float*)d_in[6];
  const float* b_hh1   = (const float*)d_in[7];
  const float* w_ih2   = (const float*)d_in[8];
  const float* w_hh2   = (const float*)d_in[9];
  const float* b_ih2   = (const float*)d_in[10];
  const float* b_hh2   = (const float*)d_in[11];
  const float* w_out   = (const float*)d_in[12];
  const float* b_out   = (const float*)d_in[13];

  char* p = (char*)d_ws;
  auto alloc = [&](size_t bytes) {
    char* r = p;
    p += (bytes + 255) & ~(size_t)255;
    return r;
  };
  float* X1      = (float*)alloc(2560ull * 1024 * 4);     // 10.5 MB
  float* XW2     = (float*)alloc(29ull * 32 * 1024 * 4);  // 3.8 MB
  float* bias1   = (float*)alloc(1024 * 4);
  float* bias2   = (float*)alloc(1024 * 4);
  float* st      = (float*)alloc(6ull * 8192 * 4);
  float* h2nf    = (float*)alloc(8192 * 4);
  u16*   H2NB    = (u16*)alloc(29ull * 8192 * 2);         // 475 KB
  float* encb    = (float*)alloc(32ull * 80 * 256 * 4);   // 2.6 MB
  float* pmaxA   = (float*)alloc(928ull * 1000 * 4);      // 3.7 MB
  float* psumA   = (float*)alloc(928ull * 1000 * 4);      // 3.7 MB
  float* tgtv    = (float*)alloc(928 * 4);
  float* lossacc = (float*)alloc(256);
  int*   targets = (int*)alloc(29 * 32 * 4);
  u16*   w_ih1b  = (u16*)alloc(1024ull * 4096 * 2);       // 8.4 MB
  u16*   w_hh1b  = (u16*)alloc(1024ull * 256 * 2);
  u16*   w_ih2rb = (u16*)alloc(1024ull * 256 * 2);
  u16*   w_hh2b  = (u16*)alloc(1024ull * 256 * 2);
  u16*   wPK     = (u16*)alloc(2000ull * 32 * 16 * 8 * 2); // 16.4 MB

  float* h1b0 = st, *h1b1 = st + 8192, *h2b0 = st + 16384, *h2b1 = st + 24576;
  float* c1 = st + 32768, *c2 = st + 40960;

  init_kernel<<<192, 256, 0, stream>>>(b_ih1, b_hh1, b_ih2, b_hh2, st, bias1, bias2, lossacc);
  conv_bf16_kernel<<<4096, 256, 0, stream>>>(w_ih1, w_ih1b, 1048576);
  conv_bf16_kernel<<<256, 256, 0, stream>>>(w_hh1, w_hh1b, 65536);
  conv_bf16_kernel<<<256, 256, 0, stream>>>(w_hh2, w_hh2b, 65536);
  conv_ih2r_kernel<<<256, 256, 0, stream>>>(w_ih2, w_ih2rb);
  pack_wout<<<4000, 256, 0, stream>>>(w_out, wPK);
  gemm_x1_kernel<<<dim3(8, 20), 256, 0, stream>>>(feat, w_ih1b, bias1, X1);
  xw2_kernel<<<dim3(29, 32), 256, 0, stream>>>(caption, w_ih2, bias2, XW2);
  argmax_kernel<<<dim3(29, 32), 256, 0, stream>>>(onehot, targets);

  StepP sp;
  sp.X1 = X1; sp.XW2 = XW2; sp.bias1 = bias1; sp.bias2 = bias2;
  sp.h1b0 = h1b0; sp.h1b1 = h1b1; sp.h2b0 = h2b0; sp.h2b1 = h2b1;
  sp.c1 = c1; sp.c2 = c2; sp.h2nf = h2nf; sp.encb = encb; sp.H2NB = H2NB;
  sp.w_hh1b = w_hh1b; sp.w_ih2rb = w_ih2rb; sp.w_hh2b = w_hh2b;

  // encoder (81 launches; t=80 also runs dec-lstm1(0))
  for (int t = 0; t <= TE; ++t)
    step_enc<<<256, 256, 0, stream>>>(sp, t);

  // decoder: 2 launches per step; attention skipped for last step (unused)
  for (int s = 0; s < TD - 1; ++s) {
    step_dec1<<<256, 256, 0, stream>>>(sp, s);
    if (s < TD - 2) step_dec2<<<32, 256, 0, stream>>>(sp, s);
  }

  logits_ce_kernel<<<250, 256, 0, stream>>>(H2NB, wPK, b_out, targets, pmaxA, psumA, tgtv);
  ce_final_kernel<<<4, 256, 0, stream>>>(pmaxA, psumA, tgtv, lossacc);
  finalize_kernel<<<1, 64, 0, stream>>>(lossacc, (float*)d_out);
}

// Round 5
// 1841.711 us; speedup vs baseline: 4.1900x; 1.1701x over previous
//
#include <hip/hip_runtime.h>
#include <hip/hip_bf16.h>
#include <math.h>

// Problem dims
#define BB 32
#define TE 80
#define FEAT 4096
#define HH 256
#define W2V 256
#define TD 30
#define VV 32000
#define G4 1024   // 4*H

typedef unsigned short u16;
typedef unsigned int u32;
using f32x4 = __attribute__((ext_vector_type(4))) float;
using bf16x8 = __attribute__((ext_vector_type(8))) short;

__device__ __forceinline__ float sigm(float x) { return 1.0f / (1.0f + expf(-x)); }
__device__ __forceinline__ u16 f2bf(float f) {
  u32 u = __float_as_uint(f);
  u32 r = (u + 0x7FFFu + ((u >> 16) & 1u)) >> 16;
  return (u16)r;
}
__device__ __forceinline__ float bflo(u32 p) { return __uint_as_float(p << 16); }
__device__ __forceinline__ float bfhi(u32 p) { return __uint_as_float(p & 0xFFFF0000u); }

#define AT_LOAD(p)     __hip_atomic_load((p), __ATOMIC_RELAXED, __HIP_MEMORY_SCOPE_AGENT)
#define AT_STORE(p, v) __hip_atomic_store((p), (v), __ATOMIC_RELAXED, __HIP_MEMORY_SCOPE_AGENT)

// ---------------------------------------------------------------------------
// init: zero H1A[0], H2A[0], counters, loss; bias sums
__global__ __launch_bounds__(256) void init_kernel(
    const float* __restrict__ b_ih1, const float* __restrict__ b_hh1,
    const float* __restrict__ b_ih2, const float* __restrict__ b_hh2,
    float* __restrict__ H1A, float* __restrict__ H2A, int* __restrict__ ctr,
    float* __restrict__ bias1, float* __restrict__ bias2,
    float* __restrict__ loss) {
  int i = blockIdx.x * 256 + threadIdx.x;
  if (i < 8192) { H1A[i] = 0.0f; H2A[i] = 0.0f; }
  if (i < 2048) ctr[i] = 0;
  if (i < 1024) {
    bias1[i] = b_ih1[i] + b_hh1[i];
    bias2[i] = b_ih2[i] + b_hh2[i];
  }
  if (i == 0) *loss = 0.0f;
}

// ---------------------------------------------------------------------------
// f32 -> bf16 contiguous (w_ih1)
__global__ __launch_bounds__(256) void conv_bf16_kernel(
    const float* __restrict__ in, u16* __restrict__ out, int n4) {
  int i = blockIdx.x * 256 + threadIdx.x;
  if (i < n4) {
    float4 v = *(const float4*)&in[(size_t)i * 4];
    *(ushort4*)&out[(size_t)i * 4] =
        make_ushort4(f2bf(v.x), f2bf(v.y), f2bf(v.z), f2bf(v.w));
  }
}

// fused small converts: w_hh1, w_hh2, w_ih2 left half, w_ih2 right half, caption
__global__ __launch_bounds__(256) void conv_small_kernel(
    const float* __restrict__ w_hh1, const float* __restrict__ w_hh2,
    const float* __restrict__ w_ih2, const float* __restrict__ caption,
    u16* __restrict__ w_hh1b, u16* __restrict__ w_hh2b,
    u16* __restrict__ w_ih2lb, u16* __restrict__ w_ih2rb,
    u16* __restrict__ capb) {
  int i = blockIdx.x * 256 + threadIdx.x;
  const float* src;
  u16* dst;
  if (i < 65536) {
    src = &w_hh1[(size_t)i * 4]; dst = &w_hh1b[(size_t)i * 4];
  } else if (i < 131072) {
    int k = i - 65536;
    src = &w_hh2[(size_t)k * 4]; dst = &w_hh2b[(size_t)k * 4];
  } else if (i < 196608) {
    int k = i - 131072, row = k >> 6, c = k & 63;
    src = &w_ih2[(size_t)row * 512 + c * 4]; dst = &w_ih2lb[(size_t)row * 256 + c * 4];
  } else if (i < 262144) {
    int k = i - 196608, row = k >> 6, c = k & 63;
    src = &w_ih2[(size_t)row * 512 + 256 + c * 4]; dst = &w_ih2rb[(size_t)row * 256 + c * 4];
  } else if (i < 323584) {
    int k = i - 262144;
    src = &caption[(size_t)k * 4]; dst = &capb[(size_t)k * 4];
  } else return;
  float4 v = *(const float4*)src;
  *(ushort4*)dst = make_ushort4(f2bf(v.x), f2bf(v.y), f2bf(v.z), f2bf(v.w));
}

// ---------------------------------------------------------------------------
// pack w_out [V][H] f32 -> wPK bf16 MFMA-B layout
__global__ __launch_bounds__(256) void pack_wout(
    const float* __restrict__ w_out, u16* __restrict__ wPK) {
  int i = blockIdx.x * 256 + threadIdx.x;  // (n, kg)
  int n = i >> 5, kg = i & 31;
  float4 v0 = *(const float4*)&w_out[(size_t)n * 256 + kg * 8];
  float4 v1 = *(const float4*)&w_out[(size_t)n * 256 + kg * 8 + 4];
  size_t dst = ((size_t)((n >> 4) * 32 + kg) * 16 + (n & 15)) * 8;
  *(ushort4*)&wPK[dst] = make_ushort4(f2bf(v0.x), f2bf(v0.y), f2bf(v0.z), f2bf(v0.w));
  *(ushort4*)&wPK[dst + 4] = make_ushort4(f2bf(v1.x), f2bf(v1.y), f2bf(v1.z), f2bf(v1.w));
}

// ---------------------------------------------------------------------------
// MFMA GEMM: X1[r][n] = feat[r][:] . w_ih1b[n][:] + bias1[n]   (r = b*80+t)
#define GBM 128
#define GBN 128
#define GBK 64
#define LDST 72

__global__ __launch_bounds__(256) void gemm_x1_kernel(
    const float* __restrict__ A, const u16* __restrict__ Bw,
    const float* __restrict__ bias, float* __restrict__ C) {
  __shared__ __align__(16) u16 As[GBM * LDST];
  __shared__ __align__(16) u16 Bs[GBN * LDST];
  int tid = threadIdx.x;
  int rBase = blockIdx.y * GBM;
  int nBase = blockIdx.x * GBN;
  int lane = tid & 63, w = tid >> 6;
  int wrow = (w >> 1) * 64, wcol = (w & 1) * 64;
  int lrow = lane & 15, lk = (lane >> 4) * 8;

  f32x4 acc[4][4];
#pragma unroll
  for (int m = 0; m < 4; ++m)
#pragma unroll
    for (int n = 0; n < 4; ++n) acc[m][n] = (f32x4){0.f, 0.f, 0.f, 0.f};

  for (int k0 = 0; k0 < FEAT; k0 += GBK) {
#pragma unroll
    for (int i = 0; i < 8; ++i) {
      int f = i * 256 + tid;
      int r = f >> 4, c = (f & 15) << 2;
      float4 v = *(const float4*)&A[(size_t)(rBase + r) * FEAT + k0 + c];
      *(ushort4*)&As[r * LDST + c] =
          make_ushort4(f2bf(v.x), f2bf(v.y), f2bf(v.z), f2bf(v.w));
    }
#pragma unroll
    for (int i = 0; i < 4; ++i) {
      int f = i * 256 + tid;
      int r = f >> 3, c = (f & 7) << 3;
      uint4 v = *(const uint4*)&Bw[(size_t)(nBase + r) * FEAT + k0 + c];
      *(uint4*)&Bs[r * LDST + c] = v;
    }
    __syncthreads();
    bf16x8 af[4][2], bfr[4][2];
#pragma unroll
    for (int m = 0; m < 4; ++m)
#pragma unroll
      for (int s2 = 0; s2 < 2; ++s2)
        af[m][s2] = *(const bf16x8*)&As[(wrow + m * 16 + lrow) * LDST + s2 * 32 + lk];
#pragma unroll
    for (int n = 0; n < 4; ++n)
#pragma unroll
      for (int s2 = 0; s2 < 2; ++s2)
        bfr[n][s2] = *(const bf16x8*)&Bs[(wcol + n * 16 + lrow) * LDST + s2 * 32 + lk];
#pragma unroll
    for (int s2 = 0; s2 < 2; ++s2)
#pragma unroll
      for (int m = 0; m < 4; ++m)
#pragma unroll
        for (int n = 0; n < 4; ++n)
          acc[m][n] = __builtin_amdgcn_mfma_f32_16x16x32_bf16(
              af[m][s2], bfr[n][s2], acc[m][n], 0, 0, 0);
    __syncthreads();
  }
  int orow = (lane >> 4) * 4;
  int ocol = lane & 15;
#pragma unroll
  for (int m = 0; m < 4; ++m)
#pragma unroll
    for (int n = 0; n < 4; ++n) {
      int cidx = nBase + wcol + n * 16 + ocol;
      float bv = bias[cidx];
#pragma unroll
      for (int q = 0; q < 4; ++q) {
        int r = rBase + wrow + m * 16 + orow + q;
        C[(size_t)r * G4 + cidx] = acc[m][n][q] + bv;
      }
    }
}

// ---------------------------------------------------------------------------
// MFMA xw2: XW2[(t*32+b)][n] = capb[b][t][:] . w_ih2lb[n][:] + bias2[n]
// grid (16 ntiles, 29 t)
__global__ __launch_bounds__(256) void xw2_mfma_kernel(
    const u16* __restrict__ capb, const u16* __restrict__ w_ih2lb,
    const float* __restrict__ bias2, float* __restrict__ XW2) {
  __shared__ __align__(16) u16 As[32 * 264];
  __shared__ __align__(16) u16 Bs[64 * 264];
  int tid = threadIdx.x;
  int nBase = blockIdx.x * 64;
  int t = blockIdx.y;
#pragma unroll
  for (int it = 0; it < 4; ++it) {
    int i = it * 256 + tid;
    int r = i >> 5, c8 = i & 31;
    *(uint4*)&As[r * 264 + c8 * 8] =
        *(const uint4*)&capb[((size_t)r * TD + t) * 256 + c8 * 8];
  }
#pragma unroll
  for (int it = 0; it < 8; ++it) {
    int i = it * 256 + tid;
    int r = i >> 5, c8 = i & 31;
    *(uint4*)&Bs[r * 264 + c8 * 8] =
        *(const uint4*)&w_ih2lb[(size_t)(nBase + r) * 256 + c8 * 8];
  }
  __syncthreads();
  int lane = tid & 63, w = tid >> 6;
  int lrow = lane & 15, lk = (lane >> 4) * 8;
  f32x4 acc[2];
  acc[0] = (f32x4){0.f, 0.f, 0.f, 0.f};
  acc[1] = (f32x4){0.f, 0.f, 0.f, 0.f};
#pragma unroll
  for (int ks = 0; ks < 8; ++ks) {
    bf16x8 bfr = *(const bf16x8*)&Bs[(w * 16 + lrow) * 264 + ks * 32 + lk];
#pragma unroll
    for (int m = 0; m < 2; ++m) {
      bf16x8 af = *(const bf16x8*)&As[(m * 16 + lrow) * 264 + ks * 32 + lk];
      acc[m] = __builtin_amdgcn_mfma_f32_16x16x32_bf16(af, bfr, acc[m], 0, 0, 0);
    }
  }
  int col = nBase + w * 16 + (lane & 15);
  float bv = bias2[col];
  int orow = (lane >> 4) * 4;
#pragma unroll
  for (int m = 0; m < 2; ++m)
#pragma unroll
    for (int q = 0; q < 4; ++q) {
      int bb = m * 16 + orow + q;
      XW2[((size_t)t * 32 + bb) * G4 + col] = acc[m][q] + bv;
    }
}

// ---------------------------------------------------------------------------
__global__ __launch_bounds__(256) void argmax_kernel(
    const float* __restrict__ onehot, int* __restrict__ targets) {
  int s = blockIdx.x + 1;
  int b = blockIdx.y;
  int tid = threadIdx.x;
  const float* row = &onehot[((size_t)b * TD + s) * VV];
  float bv = -INFINITY;
  int bi = 0x7fffffff;
  for (int v = tid; v < VV; v += 256) {
    float x = row[v];
    if (x > bv || (x == bv && v < bi)) { bv = x; bi = v; }
  }
  __shared__ float sv[256];
  __shared__ int si[256];
  sv[tid] = bv; si[tid] = bi;
  __syncthreads();
  for (int off = 128; off; off >>= 1) {
    if (tid < off) {
      float ov = sv[tid + off]; int oi = si[tid + off];
      if (ov > sv[tid] || (ov == sv[tid] && oi < si[tid])) { sv[tid] = ov; si[tid] = oi; }
    }
    __syncthreads();
  }
  if (tid == 0) targets[blockIdx.x * 32 + b] = si[0];
}

// ===========================================================================
// Persistent recurrent kernel (cooperative launch, custom LLC barriers).
// 128 L1 blocks (lstm1 chain) + 128 L2 blocks (lstm2 chain, 1 step behind).
// Cross-block data: write-once per-step arrays via agent-scope atomics.
// ===========================================================================
struct PP {
  const float *X1, *XW2, *bias1, *bias2;
  const u16 *w_hh1b, *w_ih2rb, *w_hh2b;
  float *H1A;   // [110][32][256] h1 state after T steps
  float *H2A;   // [81][32][256]  h2 state after U enc steps (1..80 = enc outputs)
  float *H2NF;  // [29][32][256]  decoder h2n (pre-attention)
  int *ctr;     // ctr[b*32] = h1 counter; ctr[(32+b)*32] = h2 counter (128B padded)
};

__device__ __forceinline__ void spin_ge(int* c, int target) {
  if (target > 0) {
    int guard = 0;
    while (AT_LOAD(c) < target && ++guard < (1 << 26)) __builtin_amdgcn_s_sleep(2);
  }
}

__device__ __forceinline__ float dot256(const uint4* __restrict__ wv,
                                        const float* h) {
  const float4* hv = (const float4*)h;
  float a = 0.f;
#pragma unroll 4
  for (int q = 0; q < 32; ++q) {
    uint4 w = wv[q];
    float4 x0 = hv[2 * q], x1 = hv[2 * q + 1];
    a += bflo(w.x) * x0.x + bfhi(w.x) * x0.y + bflo(w.y) * x0.z + bfhi(w.y) * x0.w +
         bflo(w.z) * x1.x + bfhi(w.z) * x1.y + bflo(w.w) * x1.z + bfhi(w.w) * x1.w;
  }
  return a;
}

__global__ __launch_bounds__(256, 1) void recurrent_kernel(PP p) {
  __shared__ __align__(16) float hS[256];
  __shared__ __align__(16) float h2S[256];
  __shared__ float gsm[3][64];
  __shared__ float sc[84];
  int bid = blockIdx.x;
  int tid = threadIdx.x;
  bool isL1 = bid < 128;
  int lb = isL1 ? bid : bid - 128;
  int jq = lb & 3, b = lb >> 2;
  int g = tid >> 6, jj = tid & 63;
  int j = (jq << 6) + jj;
  int row = (g << 8) + j;
  int* ctr_h1 = p.ctr + b * 32;
  int* ctr_h2 = p.ctr + (32 + b) * 32;
  float creg = 0.f;  // c-state for g==0 threads (their j)

  if (isL1) {
    const uint4* wv = (const uint4*)(p.w_hh1b + (size_t)row * 256);
    for (int T = 0; T < 109; ++T) {
      if (tid == 0) spin_ge(ctr_h1, 4 * T);
      __syncthreads();
      hS[tid] = AT_LOAD(&p.H1A[((size_t)T * 32 + b) * 256 + tid]);
      __syncthreads();
      float acc = dot256(wv, hS);
      if (g) gsm[g - 1][jj] = acc;
      __syncthreads();
      if (g == 0) {
        const float* xa = (T < TE) ? &p.X1[((size_t)b * TE + T) * G4] : p.bias1;
        float gi = acc + xa[j];
        float gf = gsm[0][jj] + xa[256 + j];
        float gg = gsm[1][jj] + xa[512 + j];
        float go = gsm[2][jj] + xa[768 + j];
        creg = sigm(gf) * creg + sigm(gi) * tanhf(gg);
        float h = sigm(go) * tanhf(creg);
        AT_STORE(&p.H1A[((size_t)(T + 1) * 32 + b) * 256 + j], h);
      }
      __syncthreads();
      if (tid == 0) {
        asm volatile("s_waitcnt vmcnt(0)" ::: "memory");
        __hip_atomic_fetch_add(ctr_h1, 1, __ATOMIC_RELAXED, __HIP_MEMORY_SCOPE_AGENT);
      }
    }
  } else {
    const uint4* w1 = (const uint4*)(p.w_ih2rb + (size_t)row * 256);
    const uint4* w2 = (const uint4*)(p.w_hh2b + (size_t)row * 256);
    for (int U = 0; U < 109; ++U) {
      if (tid == 0) {
        spin_ge(ctr_h1, 4 * (U + 1));
        spin_ge(ctr_h2, 4 * U);
      }
      __syncthreads();
      if (U <= TE) {
        // h2in = H2A[U] (enc chain state; U==80 -> final enc h2)
        h2S[tid] = AT_LOAD(&p.H2A[((size_t)U * 32 + b) * 256 + tid]);
      } else {
        // h2in = attention ctx from h2n(s-1) vs enc states
        int sp = U - TE - 1;  // previous decoder step
        hS[tid] = AT_LOAD(&p.H2NF[((size_t)sp * 32 + b) * 256 + tid]);  // q
        __syncthreads();
        if (tid < TE) {
          const float* e = &p.H2A[((size_t)(tid + 1) * 32 + b) * 256];
          float a = 0;
#pragma unroll 8
          for (int k = 0; k < 256; k++) a += e[k] * hS[k];
          sc[tid] = a;
        }
        __syncthreads();
        if (tid == 0) {
          float m = -INFINITY;
          for (int t2 = 0; t2 < TE; t2++) m = fmaxf(m, sc[t2]);
          float s2 = 0;
          for (int t2 = 0; t2 < TE; t2++) { sc[t2] = expf(sc[t2] - m); s2 += sc[t2]; }
          sc[83] = 1.0f / s2;
        }
        __syncthreads();
        float inv = sc[83];
        float a = 0;
        for (int t2 = 0; t2 < TE; t2++)
          a += sc[t2] * p.H2A[((size_t)(t2 + 1) * 32 + b) * 256 + tid];
        h2S[tid] = a * inv;
      }
      hS[tid] = AT_LOAD(&p.H1A[((size_t)(U + 1) * 32 + b) * 256 + tid]);
      __syncthreads();
      float acc = dot256(w1, hS) + dot256(w2, h2S);
      if (g) gsm[g - 1][jj] = acc;
      __syncthreads();
      if (g == 0) {
        const float* xa = (U < TE) ? p.bias2 : &p.XW2[((size_t)(U - TE) * 32 + b) * G4];
        float gi = acc + xa[j];
        float gf = gsm[0][jj] + xa[256 + j];
        float gg = gsm[1][jj] + xa[512 + j];
        float go = gsm[2][jj] + xa[768 + j];
        creg = sigm(gf) * creg + sigm(gi) * tanhf(gg);
        float h = sigm(go) * tanhf(creg);
        if (U < TE)
          AT_STORE(&p.H2A[((size_t)(U + 1) * 32 + b) * 256 + j], h);
        else
          AT_STORE(&p.H2NF[((size_t)(U - TE) * 32 + b) * 256 + j], h);
      }
      __syncthreads();
      if (tid == 0) {
        asm volatile("s_waitcnt vmcnt(0)" ::: "memory");
        __hip_atomic_fetch_add(ctr_h2, 1, __ATOMIC_RELAXED, __HIP_MEMORY_SCOPE_AGENT);
      }
    }
  }
}

// ===========================================================================
// Batched logits + fused CE partials: M=928, N=32000, K=256; A = H2NF (f32).
// ===========================================================================
__global__ __launch_bounds__(256, 1) void logits_ce_kernel(
    const float* __restrict__ H2NF, const u16* __restrict__ wPK,
    const float* __restrict__ b_out, const int* __restrict__ targets,
    float* __restrict__ pmaxA, float* __restrict__ psumA,
    float* __restrict__ tgtv) {
  __shared__ __align__(16) u16 bS[32768];
  __shared__ __align__(16) u16 aS[32 * 264];
  __shared__ int tS[32];
  int tid = threadIdx.x, bid = blockIdx.x;
  const u16* src = wPK + (size_t)bid * 32768;
  for (int i = tid; i < 4096; i += 256)
    *(uint4*)&bS[i * 8] = *(const uint4*)&src[i * 8];
  int wid = tid >> 6, lane = tid & 63, lcol = lane & 15, lk = lane >> 4;
  float bo[2];
#pragma unroll
  for (int n = 0; n < 2; ++n) bo[n] = b_out[(bid * 8 + wid * 2 + n) * 16 + lcol];

  for (int rg = 0; rg < 29; ++rg) {
    __syncthreads();
    for (int i = tid; i < 1024; i += 256) {
      int r = i >> 5, c8 = i & 31;
      const float* s = &H2NF[((size_t)rg * 32 + r) * 256 + c8 * 8];
      float4 v0 = *(const float4*)s;
      float4 v1 = *(const float4*)(s + 4);
      *(ushort4*)&aS[r * 264 + c8 * 8] =
          make_ushort4(f2bf(v0.x), f2bf(v0.y), f2bf(v0.z), f2bf(v0.w));
      *(ushort4*)&aS[r * 264 + c8 * 8 + 4] =
          make_ushort4(f2bf(v1.x), f2bf(v1.y), f2bf(v1.z), f2bf(v1.w));
    }
    if (tid < 32) tS[tid] = targets[rg * 32 + tid];
    __syncthreads();
    f32x4 acc[2][2];
#pragma unroll
    for (int m = 0; m < 2; ++m)
#pragma unroll
      for (int n = 0; n < 2; ++n) acc[m][n] = (f32x4){0.f, 0.f, 0.f, 0.f};
#pragma unroll
    for (int ks = 0; ks < 8; ++ks) {
      bf16x8 a0 = *(const bf16x8*)&aS[lcol * 264 + ks * 32 + lk * 8];
      bf16x8 a1 = *(const bf16x8*)&aS[(16 + lcol) * 264 + ks * 32 + lk * 8];
      bf16x8 b0 = *(const bf16x8*)&bS[(wid * 2) * 4096 + ((ks * 4 + lk) * 16 + lcol) * 8];
      bf16x8 b1 = *(const bf16x8*)&bS[(wid * 2 + 1) * 4096 + ((ks * 4 + lk) * 16 + lcol) * 8];
      acc[0][0] = __builtin_amdgcn_mfma_f32_16x16x32_bf16(a0, b0, acc[0][0], 0, 0, 0);
      acc[0][1] = __builtin_amdgcn_mfma_f32_16x16x32_bf16(a0, b1, acc[0][1], 0, 0, 0);
      acc[1][0] = __builtin_amdgcn_mfma_f32_16x16x32_bf16(a1, b0, acc[1][0], 0, 0, 0);
      acc[1][1] = __builtin_amdgcn_mfma_f32_16x16x32_bf16(a1, b1, acc[1][1], 0, 0, 0);
    }
    int nbase = (bid * 8 + wid * 2) * 16 + lcol;
#pragma unroll
    for (int m = 0; m < 2; ++m) {
      float pm[4], ps[4];
#pragma unroll
      for (int q = 0; q < 4; ++q) {
        float v0 = acc[m][0][q] + bo[0];
        float v1 = acc[m][1][q] + bo[1];
        int r = m * 16 + lk * 4 + q;
        int tg = tS[r];
        if (tg == nbase) tgtv[rg * 32 + r] = v0;
        if (tg == nbase + 16) tgtv[rg * 32 + r] = v1;
        float mx = fmaxf(v0, v1);
#pragma unroll
        for (int d = 1; d < 16; d <<= 1) mx = fmaxf(mx, __shfl_xor(mx, d));
        float e = expf(v0 - mx) + expf(v1 - mx);
#pragma unroll
        for (int d = 1; d < 16; d <<= 1) e += __shfl_xor(e, d);
        pm[q] = mx;
        ps[q] = e;
      }
      if (lcol == 0) {
        int chunk = bid * 4 + wid;
#pragma unroll
        for (int q = 0; q < 4; ++q) {
          int r2 = rg * 32 + m * 16 + lk * 4 + q;
          pmaxA[(size_t)r2 * 1000 + chunk] = pm[q];
          psumA[(size_t)r2 * 1000 + chunk] = ps[q];
        }
      }
    }
  }
}

// one block per row; reduce 1000 chunks
__global__ __launch_bounds__(256) void ce_final_kernel(
    const float* __restrict__ pmaxA, const float* __restrict__ psumA,
    const float* __restrict__ tgtv, float* __restrict__ loss) {
  int row = blockIdx.x;
  int tid = threadIdx.x;
  const float* pm = pmaxA + (size_t)row * 1000;
  const float* ps = psumA + (size_t)row * 1000;
  __shared__ float sm[256];
  float m = -INFINITY;
  for (int c = tid; c < 1000; c += 256) m = fmaxf(m, pm[c]);
  sm[tid] = m;
  __syncthreads();
  for (int off = 128; off; off >>= 1) {
    if (tid < off) sm[tid] = fmaxf(sm[tid], sm[tid + off]);
    __syncthreads();
  }
  float M = sm[0];
  __syncthreads();
  float s = 0.f;
  for (int c = tid; c < 1000; c += 256) s += ps[c] * expf(pm[c] - M);
  sm[tid] = s;
  __syncthreads();
  for (int off = 128; off; off >>= 1) {
    if (tid < off) sm[tid] += sm[tid + off];
    __syncthreads();
  }
  if (tid == 0)
    atomicAdd(loss, (M + logf(sm[0]) - tgtv[row]) * (1.0f / 1024.0f));
}

__global__ void finalize_kernel(const float* __restrict__ loss, float* __restrict__ out) {
  if (threadIdx.x == 0) out[0] = loss[0];
}

// ---------------------------------------------------------------------------
extern "C" void kernel_launch(void* const* d_in, const int* in_sizes, int n_in,
                              void* d_out, int out_size, void* d_ws, size_t ws_size,
                              hipStream_t stream) {
  (void)in_sizes; (void)n_in; (void)out_size; (void)ws_size;
  const float* feat    = (const float*)d_in[0];
  const float* caption = (const float*)d_in[1];
  const float* onehot  = (const float*)d_in[2];
  const float* w_ih1   = (const float*)d_in[4];
  const float* w_hh1   = (const float*)d_in[5];
  const float* b_ih1   = (const float*)d_in[6];
  const float* b_hh1   = (const float*)d_in[7];
  const float* w_ih2   = (const float*)d_in[8];
  const float* w_hh2   = (const float*)d_in[9];
  const float* b_ih2   = (const float*)d_in[10];
  const float* b_hh2   = (const float*)d_in[11];
  const float* w_out   = (const float*)d_in[12];
  const float* b_out   = (const float*)d_in[13];

  char* p = (char*)d_ws;
  auto alloc = [&](size_t bytes) {
    char* r = p;
    p += (bytes + 255) & ~(size_t)255;
    return r;
  };
  float* X1      = (float*)alloc(2560ull * 1024 * 4);      // 10.5 MB
  float* XW2     = (float*)alloc(29ull * 32 * 1024 * 4);   // 3.8 MB
  float* bias1   = (float*)alloc(1024 * 4);
  float* bias2   = (float*)alloc(1024 * 4);
  float* H1A     = (float*)alloc(110ull * 8192 * 4);       // 3.6 MB
  float* H2A     = (float*)alloc(81ull * 8192 * 4);        // 2.7 MB
  float* H2NF    = (float*)alloc(29ull * 8192 * 4);        // 0.95 MB
  int*   ctr     = (int*)alloc(2048 * 4);
  float* pmaxA   = (float*)alloc(928ull * 1000 * 4);       // 3.7 MB
  float* psumA   = (float*)alloc(928ull * 1000 * 4);       // 3.7 MB
  float* tgtv    = (float*)alloc(928 * 4);
  float* lossacc = (float*)alloc(256);
  int*   targets = (int*)alloc(29 * 32 * 4);
  u16*   w_ih1b  = (u16*)alloc(1024ull * 4096 * 2);        // 8.4 MB
  u16*   w_hh1b  = (u16*)alloc(1024ull * 256 * 2);
  u16*   w_hh2b  = (u16*)alloc(1024ull * 256 * 2);
  u16*   w_ih2lb = (u16*)alloc(1024ull * 256 * 2);
  u16*   w_ih2rb = (u16*)alloc(1024ull * 256 * 2);
  u16*   capb    = (u16*)alloc(32ull * 30 * 256 * 2);
  u16*   wPK     = (u16*)alloc(2000ull * 32 * 16 * 8 * 2); // 16.4 MB

  init_kernel<<<32, 256, 0, stream>>>(b_ih1, b_hh1, b_ih2, b_hh2, H1A, H2A, ctr,
                                      bias1, bias2, lossacc);
  conv_bf16_kernel<<<4096, 256, 0, stream>>>(w_ih1, w_ih1b, 1048576);
  conv_small_kernel<<<1264, 256, 0, stream>>>(w_hh1, w_hh2, w_ih2, caption,
                                              w_hh1b, w_hh2b, w_ih2lb, w_ih2rb, capb);
  pack_wout<<<4000, 256, 0, stream>>>(w_out, wPK);
  gemm_x1_kernel<<<dim3(8, 20), 256, 0, stream>>>(feat, w_ih1b, bias1, X1);
  xw2_mfma_kernel<<<dim3(16, 29), 256, 0, stream>>>(capb, w_ih2lb, bias2, XW2);
  argmax_kernel<<<dim3(29, 32), 256, 0, stream>>>(onehot, targets);

  PP pp;
  pp.X1 = X1; pp.XW2 = XW2; pp.bias1 = bias1; pp.bias2 = bias2;
  pp.w_hh1b = w_hh1b; pp.w_ih2rb = w_ih2rb; pp.w_hh2b = w_hh2b;
  pp.H1A = H1A; pp.H2A = H2A; pp.H2NF = H2NF; pp.ctr = ctr;
  void* args[] = {&pp};
  hipLaunchCooperativeKernel((const void*)recurrent_kernel, dim3(256), dim3(256),
                             args, 0, stream);

  logits_ce_kernel<<<250, 256, 0, stream>>>(H2NF, wPK, b_out, targets, pmaxA, psumA, tgtv);
  ce_final_kernel<<<928, 256, 0, stream>>>(pmaxA, psumA, tgtv, lossacc);
  finalize_kernel<<<1, 64, 0, stream>>>(lossacc, (float*)d_out);
}